// Round 15
// baseline (141.038 us; speedup 1.0000x reference)
//
#include <hip/hip_runtime.h>
#include <hip/hip_bf16.h>
#include <stdint.h>

#define N_NODES 100000
#define N_EDGES 1600000
#define IN_DIM 128
#define HID_DIM 128
#define OUT_DIM 64
#define NBUCKET 391   // ceil(N_NODES/256), bucket = dst>>8
#define NBE 391       // edge blocks, 4096 edges each
#define ECHUNK 4096
#define HM (NBUCKET * NBE)          // 152881 hist entries
#define NB_SCAN 150                 // ceil(HM/1024)
#define SENTINEL N_NODES            // padded-slot src -> zero row
#define PCAP 6144                   // fixed padded bucket capacity (+32 sigma)
#define GEMM_ROWBLKS 782            // ceil(N_NODES/128)

typedef __bf16 bf16x8 __attribute__((ext_vector_type(8)));
typedef float f32x4 __attribute__((ext_vector_type(4)));
typedef float f32x2 __attribute__((ext_vector_type(2)));

__device__ __forceinline__ uint16_t f_to_bf16(float f) {
    uint32_t u = __float_as_uint(f);
    u += 0x7fffu + ((u >> 16) & 1u);   // round-to-nearest-even
    return (uint16_t)(u >> 16);
}
__device__ __forceinline__ uint32_t pack_bf16x2(float lo, float hi) {
    return (uint32_t)f_to_bf16(lo) | ((uint32_t)f_to_bf16(hi) << 16);
}

// ---------------- fused prep: edge histogram + x fp8 cast + weight transpose ----------------

__global__ __launch_bounds__(256) void prep_k(const int* __restrict__ dst,
                                              const float* __restrict__ x,
                                              const float* __restrict__ W1l,
                                              const float* __restrict__ W1r,
                                              const float* __restrict__ W2l,
                                              const float* __restrict__ W2r,
                                              int* __restrict__ hist,
                                              uint32_t* __restrict__ xf8,
                                              uint16_t* __restrict__ wT1,
                                              uint16_t* __restrict__ wT2) {
    __shared__ int lh[NBUCKET];
    int blk = blockIdx.x, t = threadIdx.x;
    if (blk < NBE) {
        for (int i = t; i < NBUCKET; i += 256) lh[i] = 0;
        __syncthreads();
        int e0 = blk * ECHUNK;
        int e1 = e0 + ECHUNK; if (e1 > N_EDGES) e1 = N_EDGES;
        for (int e = e0 + t; e < e1; e += 256) atomicAdd(&lh[dst[e] >> 8], 1);
        __syncthreads();
        for (int i = t; i < NBUCKET; i += 256) hist[i * NBE + blk] = lh[i];
    } else if (blk < NBE + 6250) {
        int i = (blk - NBE) * 256 + t;   // 8 floats per thread
        if (blk == NBE && t < 32) xf8[N_NODES * 32 + t] = 0u;  // sentinel zero row
        if (i >= N_NODES * IN_DIM / 8) return;
        const float4* xv = (const float4*)x;
        float4 v0 = xv[2 * i], v1 = xv[2 * i + 1];
        int p0 = __builtin_amdgcn_cvt_pk_fp8_f32(v0.x, v0.y, 0, false);
        p0 = __builtin_amdgcn_cvt_pk_fp8_f32(v0.z, v0.w, p0, true);
        int p1 = __builtin_amdgcn_cvt_pk_fp8_f32(v1.x, v1.y, 0, false);
        p1 = __builtin_amdgcn_cvt_pk_fp8_f32(v1.z, v1.w, p1, true);
        uint2 w2; w2.x = (uint32_t)p0; w2.y = (uint32_t)p1;
        ((uint2*)xf8)[i] = w2;
    } else {
        int i = (blk - NBE - 6250) * 256 + t;
        if (i < 128 * 256) {
            int n = i >> 8, k = i & 255;
            float v = (k < 128) ? W1l[k * 128 + n] : W1r[(k - 128) * 128 + n];
            wT1[i] = f_to_bf16(v);
        } else {
            int j = i - 128 * 256;
            if (j < 128 * 128) {
                int n = j >> 7, k = j & 127;
                float v = (n < 64) ? W2l[k * 64 + n] : W2r[k * 64 + (n - 64)];
                wT2[j] = f_to_bf16(v);
            }
        }
    }
}

// ---------------- scan of the 391x391 hist matrix ----------------

__global__ void scan1_k(int* __restrict__ data, int* __restrict__ partials, int n) {
    __shared__ int sm[256];
    int tid = threadIdx.x;
    int base = blockIdx.x * 1024 + tid * 4;
    int v0 = 0, v1 = 0, v2 = 0, v3 = 0;
    if (base + 0 < n) v0 = data[base + 0];
    if (base + 1 < n) v1 = data[base + 1];
    if (base + 2 < n) v2 = data[base + 2];
    if (base + 3 < n) v3 = data[base + 3];
    int tot = v0 + v1 + v2 + v3;
    sm[tid] = tot;
    __syncthreads();
    int val = tot;
    for (int off = 1; off < 256; off <<= 1) {
        int x = (tid >= off) ? sm[tid - off] : 0;
        __syncthreads();
        val += x;
        sm[tid] = val;
        __syncthreads();
    }
    int excl = val - tot;
    if (tid == 255) partials[blockIdx.x] = val;
    if (base + 0 < n) data[base + 0] = excl;
    if (base + 1 < n) data[base + 1] = excl + v0;
    if (base + 2 < n) data[base + 2] = excl + v0 + v1;
    if (base + 3 < n) data[base + 3] = excl + v0 + v1 + v2;
}

// fused: re-scan the 150 block partials in LDS, then add to elements
__global__ void scan3_k(int* __restrict__ data, const int* __restrict__ partials, int n) {
    __shared__ int sm[256];
    __shared__ int sp[256];
    int t = threadIdx.x;
    int v = (t < NB_SCAN) ? partials[t] : 0;
    sm[t] = v;
    __syncthreads();
    int val = v;
    for (int off = 1; off < 256; off <<= 1) {
        int x = (t >= off) ? sm[t - off] : 0;
        __syncthreads();
        val += x;
        sm[t] = val;
        __syncthreads();
    }
    sp[t] = val - v;   // exclusive
    __syncthreads();
    int i = blockIdx.x * 256 + t;
    if (i < n) data[i] += sp[i >> 10];
}

__global__ __launch_bounds__(256) void scatter2_k(const int* __restrict__ src,
                                                  const int* __restrict__ dst,
                                                  const int* __restrict__ hoff,
                                                  uint32_t* __restrict__ packed) {
    __shared__ int loff[NBUCKET];
    int blk = blockIdx.x, t = threadIdx.x;
    for (int i = t; i < NBUCKET; i += 256) loff[i] = hoff[i * NBE + blk];
    __syncthreads();
    int e0 = blk * ECHUNK;
    int e1 = e0 + ECHUNK; if (e1 > N_EDGES) e1 = N_EDGES;
    for (int e = e0 + t; e < e1; e += 256) {
        int d = dst[e];
        int pos = atomicAdd(&loff[d >> 8], 1);
        packed[pos] = ((uint32_t)src[e] << 8) | (uint32_t)(d & 255);
    }
}

// ---------------- fused finalize: hist + padded scan + sentinel CSR, fixed-cap buckets ---

__global__ __launch_bounds__(256) void finalize_k(const uint32_t* __restrict__ packed,
                                                  const int* __restrict__ hoff,
                                                  int* __restrict__ csr,
                                                  int* __restrict__ deg,
                                                  int* __restrict__ prowst) {
    __shared__ int lhist[256];
    __shared__ int ssc[256];
    __shared__ int lcur[256];
    __shared__ int s_pcnt;
    __shared__ uint32_t lpk[PCAP];
    __shared__ int lcsr[PCAP];
    int b = blockIdx.x, t = threadIdx.x;
    int base = hoff[b * NBE];
    int next = (b + 1 < NBUCKET) ? hoff[(b + 1) * NBE] : N_EDGES;
    int cnt = next - base;
    lhist[t] = 0;
    __syncthreads();
    bool fit = (cnt <= PCAP);
    if (fit) {
        for (int i = t; i < cnt; i += 256) {
            uint32_t pk = packed[base + i];
            lpk[i] = pk;
            atomicAdd(&lhist[pk & 255u], 1);
        }
    } else {
        for (int i = t; i < cnt; i += 256) atomicAdd(&lhist[packed[base + i] & 255u], 1);
    }
    __syncthreads();
    int d = lhist[t];
    int pd = (d + 7) & ~7;
    ssc[t] = pd;
    __syncthreads();
    int val = pd;
    for (int off = 1; off < 256; off <<= 1) {
        int x = (t >= off) ? ssc[t - off] : 0;
        __syncthreads();
        val += x;
        ssc[t] = val;
        __syncthreads();
    }
    int excl = val - pd;
    lcur[t] = excl;
    if (t == 255) s_pcnt = val;
    int node = (b << 8) + t;
    if (node < N_NODES) { deg[node] = d; prowst[node] = b * PCAP + excl; }
    __syncthreads();
    int pcnt = s_pcnt;
    int cbase = b * PCAP;
    if (fit && pcnt <= PCAP) {
        for (int i = t; i < pcnt; i += 256) lcsr[i] = SENTINEL;
        __syncthreads();
        for (int i = t; i < cnt; i += 256) {
            uint32_t pk = lpk[i];
            int pos = atomicAdd(&lcur[pk & 255u], 1);
            lcsr[pos] = (int)(pk >> 8);
        }
        __syncthreads();
        for (int i = t; i < pcnt; i += 256) csr[cbase + i] = lcsr[i];
    } else {  // statistically unreachable (+32 sigma); stays within slice
        int lim = pcnt < PCAP ? pcnt : PCAP;
        for (int i = t; i < lim; i += 256) csr[cbase + i] = SENTINEL;
        __syncthreads();
        for (int i = t; i < cnt; i += 256) {
            uint32_t pk = packed[base + i];
            int pos = atomicAdd(&lcur[pk & 255u], 1);
            if (pos < PCAP) csr[cbase + pos] = (int)(pk >> 8);
        }
    }
}

// ---------------- layer-1 mean aggregation: 2 nodes/wave, coalesced gather ----
// half-wave (32 lanes) owns one node; lane covers 4 B of the 128 B fp8 row.
// output fp8 (uint32/lane = cols 4c..4c+3) — halves the ab round-trip.

__global__ void aggregate_k(const int* __restrict__ csr, const int* __restrict__ prowst,
                            const int* __restrict__ deg,
                            const uint32_t* __restrict__ inf8, uint32_t* __restrict__ outf8) {
    int gw = (blockIdx.x * blockDim.x + threadIdx.x) >> 6;
    int lane = threadIdx.x & 63;
    int c = lane & 31, p = lane >> 5;
    int node = 2 * gw + p;                 // grid exact: 50000 waves x 2 = 100000
    int start = prowst[node];
    int d = deg[node];
    int pd = (d + 7) & ~7;
    f32x2 s01 = (f32x2){0.f, 0.f}, s23 = (f32x2){0.f, 0.f};
    for (int j = 0; j < pd; j += 8) {
        uint32_t q[8];
#pragma unroll
        for (int u = 0; u < 8; u++) {
            int s = csr[start + j + u];
            q[u] = inf8[(s << 5) + c];
        }
#pragma unroll
        for (int u = 0; u < 8; u++) {
            s01 += __builtin_amdgcn_cvt_pk_f32_fp8((int)q[u], false);
            s23 += __builtin_amdgcn_cvt_pk_f32_fp8((int)q[u], true);
        }
    }
    float inv = 1.0f / (float)(d > 0 ? d : 1);
    int pk = __builtin_amdgcn_cvt_pk_fp8_f32(s01[0] * inv, s01[1] * inv, 0, false);
    pk = __builtin_amdgcn_cvt_pk_fp8_f32(s23[0] * inv, s23[1] * inv, pk, true);
    outf8[node * 32 + c] = (uint32_t)pk;   // 128 B/row contiguous per half-wave
}

// ---------------- fused GEMM1+GEMM2: per 128-row block, both layers, no hb round-trip ----
// A1 fragments read from fp8 aggregate (exact fp8->bf16 replay; e4m3 subset of bf16);
// A2 (root) stays fp32 — r14 proved fp8-x in the root term exceeds the error budget.
// A fragments hoisted out of the nh loop (r12). z bf16 (r11).
// Phase 1 (x2 col-halves): stage wT1-half (32KB) -> MFMA -> bias+relu -> lhb (XOR-chunk).
// Phase 2: restage lwA with wT2 -> MFMA A<-lhb, B<-lwA -> g fp8 + z bf16 epilogues.

__global__ __launch_bounds__(256, 2) void gemm12_k(const uint32_t* __restrict__ abf8,
                                                   const float* __restrict__ x,
                                                   const uint16_t* __restrict__ wT1,
                                                   const float* __restrict__ b1,
                                                   const uint16_t* __restrict__ wT2,
                                                   const float* __restrict__ b2,
                                                   uint8_t* __restrict__ g,
                                                   uint16_t* __restrict__ zb) {
    __shared__ uint16_t lwA[64 * 256];   // 32 KB: wT1-half, then wT2, then fp8 epilogue
    __shared__ uint16_t lhb[128 * 128];  // 32 KB: h tile (XOR-chunk), then z bf16 epilogue
    int t = threadIdx.x;
    int rowblk = blockIdx.x;
    if (rowblk == 0 && t < 16)
        ((uint32_t*)(g + (size_t)N_NODES * 64))[t] = 0u;  // sentinel zero row

    int wave = t >> 6;
    int lane = t & 63;
    int m0 = rowblk * 128 + wave * 32;
    int mr = lane & 15, quad = lane >> 4;

    const uint32_t* A1[2];
    const float* A2[2];
#pragma unroll
    for (int s = 0; s < 2; s++) {
        int row = m0 + s * 16 + mr;
        if (row > N_NODES - 1) row = N_NODES - 1;   // clamp (stores still guarded)
        A1[s] = abf8 + (size_t)row * 32 + quad * 2;
        A2[s] = x + (size_t)row * 128 + quad * 8;
    }

    // ---------------- hoisted A-fragment loads (once per block; overlap wT1 stage) ----
    bf16x8 afr[8][2];
#pragma unroll
    for (int kt = 0; kt < 8; kt++) {
#pragma unroll
        for (int s = 0; s < 2; s++) {
            if (kt < 4) {
                uint2 w = *reinterpret_cast<const uint2*>(A1[s] + kt * 8);
                f32x2 a0 = __builtin_amdgcn_cvt_pk_f32_fp8((int)w.x, false);
                f32x2 a1 = __builtin_amdgcn_cvt_pk_f32_fp8((int)w.x, true);
                f32x2 a2 = __builtin_amdgcn_cvt_pk_f32_fp8((int)w.y, false);
                f32x2 a3 = __builtin_amdgcn_cvt_pk_f32_fp8((int)w.y, true);
                union { uint32_t w[4]; bf16x8 v; } cv;
                cv.w[0] = pack_bf16x2(a0[0], a0[1]);
                cv.w[1] = pack_bf16x2(a1[0], a1[1]);
                cv.w[2] = pack_bf16x2(a2[0], a2[1]);
                cv.w[3] = pack_bf16x2(a3[0], a3[1]);
                afr[kt][s] = cv.v;
            } else {
                const float* ap = A2[s] + (kt - 4) * 32;
                float4 f0 = *reinterpret_cast<const float4*>(ap);
                float4 f1 = *reinterpret_cast<const float4*>(ap + 4);
                union { uint16_t u[8]; bf16x8 v; } cv;
                cv.u[0] = f_to_bf16(f0.x); cv.u[1] = f_to_bf16(f0.y);
                cv.u[2] = f_to_bf16(f0.z); cv.u[3] = f_to_bf16(f0.w);
                cv.u[4] = f_to_bf16(f1.x); cv.u[5] = f_to_bf16(f1.y);
                cv.u[6] = f_to_bf16(f1.z); cv.u[7] = f_to_bf16(f1.w);
                afr[kt][s] = cv.v;
            }
        }
    }

    // ---------------- phase 1: two col-halves of h ----------------
    for (int nh = 0; nh < 2; nh++) {
        {   // stage wT1-half: global chunk (row nh*64+r, cc) -> lds r*32 + (cc^(r&31))
            const uint4* gsrc = (const uint4*)wT1;
            uint4* ldst = (uint4*)lwA;
            for (int i = t; i < 2048; i += 256) {
                int r = i >> 5, cc = i & 31;
                ldst[(r << 5) + (cc ^ (r & 31))] = gsrc[((nh * 64 + r) << 5) + cc];
            }
        }
        __syncthreads();

        f32x4 acc[4][2];
#pragma unroll
        for (int nt = 0; nt < 4; nt++)
#pragma unroll
            for (int s = 0; s < 2; s++) acc[nt][s] = (f32x4){0.f, 0.f, 0.f, 0.f};

#pragma unroll
        for (int kt = 0; kt < 8; kt++) {
#pragma unroll
            for (int nt = 0; nt < 4; nt++) {
                int brow = nt * 16 + mr;              // local 0..63
                int chunk = kt * 4 + quad;
                const uint16_t* bp = lwA + (brow << 8) + ((chunk ^ (brow & 31)) << 3);
                bf16x8 b = *reinterpret_cast<const bf16x8*>(bp);
#pragma unroll
                for (int s = 0; s < 2; s++)
                    acc[nt][s] = __builtin_amdgcn_mfma_f32_16x16x32_bf16(afr[kt][s], b, acc[nt][s], 0, 0, 0);
            }
        }
        __syncthreads();   // lwA reads done (safe to restage next iter / wT2)

        // bias+relu -> lhb (h cols nh*64 .. nh*64+63), XOR-chunk layout
#pragma unroll
        for (int nt = 0; nt < 4; nt++) {
            int col = nh * 64 + nt * 16 + mr;        // global h col 0..127
            float bias = b1[col];
            int c2 = col >> 3, clo = col & 7;
#pragma unroll
            for (int s = 0; s < 2; s++) {
#pragma unroll
                for (int r = 0; r < 4; r++) {
                    int lrow = wave * 32 + s * 16 + quad * 4 + r;   // 0..127
                    float v = acc[nt][s][r] + bias;
                    v = v > 0.f ? v : 0.f;
                    lhb[(lrow << 7) + ((c2 ^ (lrow & 15)) << 3) + clo] = f_to_bf16(v);
                }
            }
        }
        // no barrier needed here: lhb writes only conflict with phase-2 reads,
        // guarded by the barrier after wT2 staging
    }

    // ---------------- phase 2: [g|z] = h @ wT2 ----------------
    {   // stage full wT2: chunk i = (r = i>>4, cc = i&15) -> lds r*16 + (cc^(r&15))
        const uint4* gsrc = (const uint4*)wT2;
        uint4* ldst = (uint4*)lwA;
        for (int i = t; i < 2048; i += 256) {
            int r = i >> 4, cc = i & 15;
            ldst[(r << 4) + (cc ^ (r & 15))] = gsrc[(r << 4) + cc];
        }
    }
    __syncthreads();   // wT2 staged AND all lhb writes visible

    f32x4 acc2[8][2];
#pragma unroll
    for (int nt = 0; nt < 8; nt++)
#pragma unroll
        for (int s = 0; s < 2; s++) acc2[nt][s] = (f32x4){0.f, 0.f, 0.f, 0.f};

#pragma unroll
    for (int kt = 0; kt < 4; kt++) {
        bf16x8 av[2];
#pragma unroll
        for (int s = 0; s < 2; s++) {
            int row = wave * 32 + s * 16 + mr;       // local 0..127
            int chunk = kt * 4 + quad;
            const uint16_t* ap = lhb + (row << 7) + ((chunk ^ (row & 15)) << 3);
            av[s] = *reinterpret_cast<const bf16x8*>(ap);
        }
#pragma unroll
        for (int nt = 0; nt < 8; nt++) {
            int brow = nt * 16 + mr;                 // product col 0..127
            int chunk = kt * 4 + quad;
            const uint16_t* bp = lwA + (brow << 7) + ((chunk ^ (brow & 15)) << 3);
            bf16x8 b = *reinterpret_cast<const bf16x8*>(bp);
#pragma unroll
            for (int s = 0; s < 2; s++)
                acc2[nt][s] = __builtin_amdgcn_mfma_f32_16x16x32_bf16(av[s], b, acc2[nt][s], 0, 0, 0);
        }
    }

    // ---------------- epilogues: stage both outputs in LDS, store coalesced ----
    __syncthreads();   // all lhb + lwA reads done; both buffers reusable
    {
        // z (product cols 64..127) -> bf16 into lhb as [128][72] (stride 144B)
#pragma unroll
        for (int nt = 4; nt < 8; nt++) {
            int zcol = nt * 16 + mr - 64;            // 0..63
            float bias = b2[zcol];
#pragma unroll
            for (int s = 0; s < 2; s++) {
#pragma unroll
                for (int r = 0; r < 4; r++) {
                    int lrow = wave * 32 + s * 16 + quad * 4 + r;
                    lhb[lrow * 72 + zcol] = f_to_bf16(acc2[nt][s][r] + bias);
                }
            }
        }
        // g (product cols 0..63) -> fp8 into lwA as [128][80] bytes
        uint8_t* ep8 = (uint8_t*)lwA;
#pragma unroll
        for (int nt = 0; nt < 4; nt++) {
            int col = nt * 16 + mr;
#pragma unroll
            for (int s = 0; s < 2; s++) {
#pragma unroll
                for (int r = 0; r < 4; r++) {
                    int lrow = wave * 32 + s * 16 + quad * 4 + r;
                    float v = acc2[nt][s][r];
                    int pk = __builtin_amdgcn_cvt_pk_fp8_f32(v, v, 0, false);
                    ep8[lrow * 80 + col] = (uint8_t)(pk & 0xff);
                }
            }
        }
        __syncthreads();
        int rows0 = rowblk * 128;
        // g store: 128 rows x 64 B = 512 x 16B chunks
        for (int c2 = t; c2 < 512; c2 += 256) {
            int r = c2 >> 2, part = c2 & 3;
            int grow = rows0 + r;
            if (grow < N_NODES) {
                uint4 v = *reinterpret_cast<const uint4*>(ep8 + r * 80 + part * 16);
                *reinterpret_cast<uint4*>(g + (size_t)grow * 64 + part * 16) = v;
            }
        }
        // z store: 128 rows x 128 B (64 bf16) = 1024 x 16B chunks
        for (int c2 = t; c2 < 1024; c2 += 256) {
            int r = c2 >> 3, part = c2 & 7;
            int grow = rows0 + r;
            if (grow < N_NODES) {
                uint4 v = *reinterpret_cast<const uint4*>(lhb + r * 72 + part * 8);
                *reinterpret_cast<uint4*>(zb + (size_t)grow * 64 + part * 8) = v;
            }
        }
    }
}

// ---------------- layer-2 aggregation: 4 nodes/wave, coalesced gather ----
// quarter-wave (16 lanes) owns one node; lane covers 4 B of the 64 B fp8 row.
// z read is bf16 (uint2 = 4 cols/lane), converted in-register.

__global__ void agg2_k(const int* __restrict__ csr, const int* __restrict__ prowst,
                       const int* __restrict__ deg,
                       const uint32_t* __restrict__ g4, const uint16_t* __restrict__ zb,
                       float* __restrict__ out) {
    int gw = (blockIdx.x * blockDim.x + threadIdx.x) >> 6;
    int lane = threadIdx.x & 63;
    int c = lane & 15, q4 = lane >> 4;
    int node = 4 * gw + q4;                // grid exact: 25000 waves x 4 = 100000
    int start = prowst[node];
    int d = deg[node];
    int pd = (d + 7) & ~7;
    f32x2 s01 = (f32x2){0.f, 0.f}, s23 = (f32x2){0.f, 0.f};
    for (int j = 0; j < pd; j += 8) {
        uint32_t q[8];
#pragma unroll
        for (int u = 0; u < 8; u++) {
            int s = csr[start + j + u];
            q[u] = g4[(s << 4) + c];
        }
#pragma unroll
        for (int u = 0; u < 8; u++) {
            s01 += __builtin_amdgcn_cvt_pk_f32_fp8((int)q[u], false);
            s23 += __builtin_amdgcn_cvt_pk_f32_fp8((int)q[u], true);
        }
    }
    float inv = 1.0f / (float)(d > 0 ? d : 1);
    uint2 zw = ((const uint2*)zb)[node * 16 + c];   // 4 bf16 = cols 4c..4c+3
    float4 o;
    o.x = s01[0] * inv + __uint_as_float((zw.x & 0xffffu) << 16);
    o.y = s01[1] * inv + __uint_as_float(zw.x & 0xffff0000u);
    o.z = s23[0] * inv + __uint_as_float((zw.y & 0xffffu) << 16);
    o.w = s23[1] * inv + __uint_as_float(zw.y & 0xffff0000u);
    ((float4*)out)[node * 16 + c] = o;     // full-wave store, 4 rows / instr
}

// ---------------- launch ----------------

extern "C" void kernel_launch(void* const* d_in, const int* in_sizes, int n_in,
                              void* d_out, int out_size, void* d_ws, size_t ws_size,
                              hipStream_t stream) {
    const float* x   = (const float*)d_in[0];
    const int*  ei   = (const int*)d_in[1];
    const float* W1l = (const float*)d_in[2];
    const float* b1  = (const float*)d_in[3];
    const float* W1r = (const float*)d_in[4];
    const float* W2l = (const float*)d_in[5];
    const float* b2  = (const float*)d_in[6];
    const float* W2r = (const float*)d_in[7];
    float* out = (float*)d_out;

    const int* srcv = ei;            // edge_index[0]
    const int* dstv = ei + N_EDGES;  // edge_index[1]

    char* ws = (char*)d_ws;
    int*      deg      = (int*)(ws + 0);              // 100000 ints
    int*      prowst   = (int*)(ws + 401408);         // 100000 ints (padded row starts)
    int*      partials = (int*)(ws + 802816);         // 150 ints
    int*      csr      = (int*)(ws + 1209344);        // 391*PCAP ints = 9.6 MB -> 10818560
    uint16_t* wT1      = (uint16_t*)(ws + 13809664);  // 64 KB
    uint16_t* wT2      = (uint16_t*)(ws + 13875200);  // 32 KB
    uint8_t*  g        = (uint8_t*)(ws + 13907968);   // fp8 g (6.4 MB + 64B sentinel) -> 20308032
    uint16_t* zb       = (uint16_t*)(ws + 20308096);  // bf16 z (12.8 MB) -> 33108096
    uint32_t* abf8     = (uint32_t*)(ws + 39507968);  // fp8 aggregate (12.8 MB) -> 52307968
    // scratch region (former hb slot; consumed before gemm12 runs; stream-ordered):
    uint32_t* packed   = (uint32_t*)(ws + 65107968);          // 6.4 MB
    int*      hoff     = (int*)(ws + 65107968 + 6400000);     // 611 KB
    uint32_t* xf8      = (uint32_t*)(ws + 65107968 + 7013376);// 12.8 MB + 128

    // fused prep: hist + fp8 cast + weight transpose (independent block ranges)
    prep_k<<<NBE + 6250 + 192, 256, 0, stream>>>(dstv, x, W1l, W1r, W2l, W2r,
                                                 hoff, xf8, wT1, wT2);
    // scan hist matrix -> bucket-major global offsets
    scan1_k<<<NB_SCAN, 256, 0, stream>>>(hoff, partials, HM);
    scan3_k<<<(HM + 255) / 256, 256, 0, stream>>>(hoff, partials, HM);
    // partition edges into bucket-contiguous packed array
    scatter2_k<<<NBE, 256, 0, stream>>>(srcv, dstv, hoff, packed);
    // per-bucket padded CSR + deg + prowst (fixed-cap slices)
    finalize_k<<<NBUCKET, 256, 0, stream>>>(packed, hoff, csr, deg, prowst);

    // layer 1 aggregation: aggr(x_fp8) -> abf8 (fp8)
    aggregate_k<<<12500, 256, 0, stream>>>(csr, prowst, deg, xf8, abf8);
    // fused both GEMMs: h = relu([aggr|x]@wT1^T + b1) in LDS; [g|zb] = h@wT2 (+b2 on z)
    gemm12_k<<<GEMM_ROWBLKS, 256, 0, stream>>>(abf8, x, wT1, b1, wT2, b2, g, zb);
    // layer 2 aggregation: out = mean-aggr(g) + z
    agg2_k<<<6250, 256, 0, stream>>>(csr, prowst, deg, (const uint32_t*)g, zb, out);
}

// Round 16
// 135.493 us; speedup vs baseline: 1.0409x; 1.0409x over previous
//
#include <hip/hip_runtime.h>
#include <hip/hip_bf16.h>
#include <stdint.h>

#define N_NODES 100000
#define N_EDGES 1600000
#define IN_DIM 128
#define HID_DIM 128
#define OUT_DIM 64
#define NBUCKET 391   // ceil(N_NODES/256), bucket = dst>>8
#define NBE 391       // edge blocks, 4096 edges each
#define ECHUNK 4096
#define HM (NBUCKET * NBE)          // 152881 hist entries
#define NB_SCAN 150                 // ceil(HM/1024)
#define SENTINEL N_NODES            // padded-slot src -> zero row
#define PCAP 6144                   // fixed padded bucket capacity (+32 sigma)
#define GEMM_ROWBLKS 782            // ceil(N_NODES/128)

typedef __bf16 bf16x8 __attribute__((ext_vector_type(8)));
typedef float f32x4 __attribute__((ext_vector_type(4)));
typedef float f32x2 __attribute__((ext_vector_type(2)));

__device__ __forceinline__ uint16_t f_to_bf16(float f) {
    uint32_t u = __float_as_uint(f);
    u += 0x7fffu + ((u >> 16) & 1u);   // round-to-nearest-even
    return (uint16_t)(u >> 16);
}
__device__ __forceinline__ uint32_t pack_bf16x2(float lo, float hi) {
    return (uint32_t)f_to_bf16(lo) | ((uint32_t)f_to_bf16(hi) << 16);
}

// ---------------- fused prep: edge histogram + x fp8 cast + weight transpose ----------------

__global__ __launch_bounds__(256) void prep_k(const int* __restrict__ dst,
                                              const float* __restrict__ x,
                                              const float* __restrict__ W1l,
                                              const float* __restrict__ W1r,
                                              const float* __restrict__ W2l,
                                              const float* __restrict__ W2r,
                                              int* __restrict__ hist,
                                              uint32_t* __restrict__ xf8,
                                              uint16_t* __restrict__ wT1,
                                              uint16_t* __restrict__ wT2) {
    __shared__ int lh[NBUCKET];
    int blk = blockIdx.x, t = threadIdx.x;
    if (blk < NBE) {
        for (int i = t; i < NBUCKET; i += 256) lh[i] = 0;
        __syncthreads();
        int e0 = blk * ECHUNK;
        int e1 = e0 + ECHUNK; if (e1 > N_EDGES) e1 = N_EDGES;
        for (int e = e0 + t; e < e1; e += 256) atomicAdd(&lh[dst[e] >> 8], 1);
        __syncthreads();
        for (int i = t; i < NBUCKET; i += 256) hist[i * NBE + blk] = lh[i];
    } else if (blk < NBE + 6250) {
        int i = (blk - NBE) * 256 + t;   // 8 floats per thread
        if (blk == NBE && t < 32) xf8[N_NODES * 32 + t] = 0u;  // sentinel zero row
        if (i >= N_NODES * IN_DIM / 8) return;
        const float4* xv = (const float4*)x;
        float4 v0 = xv[2 * i], v1 = xv[2 * i + 1];
        int p0 = __builtin_amdgcn_cvt_pk_fp8_f32(v0.x, v0.y, 0, false);
        p0 = __builtin_amdgcn_cvt_pk_fp8_f32(v0.z, v0.w, p0, true);
        int p1 = __builtin_amdgcn_cvt_pk_fp8_f32(v1.x, v1.y, 0, false);
        p1 = __builtin_amdgcn_cvt_pk_fp8_f32(v1.z, v1.w, p1, true);
        uint2 w2; w2.x = (uint32_t)p0; w2.y = (uint32_t)p1;
        ((uint2*)xf8)[i] = w2;
    } else {
        int i = (blk - NBE - 6250) * 256 + t;
        if (i < 128 * 256) {
            int n = i >> 8, k = i & 255;
            float v = (k < 128) ? W1l[k * 128 + n] : W1r[(k - 128) * 128 + n];
            wT1[i] = f_to_bf16(v);
        } else {
            int j = i - 128 * 256;
            if (j < 128 * 128) {
                int n = j >> 7, k = j & 127;
                float v = (n < 64) ? W2l[k * 64 + n] : W2r[k * 64 + (n - 64)];
                wT2[j] = f_to_bf16(v);
            }
        }
    }
}

// ---------------- scan of the 391x391 hist matrix ----------------

__global__ void scan1_k(int* __restrict__ data, int* __restrict__ partials, int n) {
    __shared__ int sm[256];
    int tid = threadIdx.x;
    int base = blockIdx.x * 1024 + tid * 4;
    int v0 = 0, v1 = 0, v2 = 0, v3 = 0;
    if (base + 0 < n) v0 = data[base + 0];
    if (base + 1 < n) v1 = data[base + 1];
    if (base + 2 < n) v2 = data[base + 2];
    if (base + 3 < n) v3 = data[base + 3];
    int tot = v0 + v1 + v2 + v3;
    sm[tid] = tot;
    __syncthreads();
    int val = tot;
    for (int off = 1; off < 256; off <<= 1) {
        int x = (tid >= off) ? sm[tid - off] : 0;
        __syncthreads();
        val += x;
        sm[tid] = val;
        __syncthreads();
    }
    int excl = val - tot;
    if (tid == 255) partials[blockIdx.x] = val;
    if (base + 0 < n) data[base + 0] = excl;
    if (base + 1 < n) data[base + 1] = excl + v0;
    if (base + 2 < n) data[base + 2] = excl + v0 + v1;
    if (base + 3 < n) data[base + 3] = excl + v0 + v1 + v2;
}

// fused: re-scan the 150 block partials in LDS, then add to elements
__global__ void scan3_k(int* __restrict__ data, const int* __restrict__ partials, int n) {
    __shared__ int sm[256];
    __shared__ int sp[256];
    int t = threadIdx.x;
    int v = (t < NB_SCAN) ? partials[t] : 0;
    sm[t] = v;
    __syncthreads();
    int val = v;
    for (int off = 1; off < 256; off <<= 1) {
        int x = (t >= off) ? sm[t - off] : 0;
        __syncthreads();
        val += x;
        sm[t] = val;
        __syncthreads();
    }
    sp[t] = val - v;   // exclusive
    __syncthreads();
    int i = blockIdx.x * 256 + t;
    if (i < n) data[i] += sp[i >> 10];
}

__global__ __launch_bounds__(256) void scatter2_k(const int* __restrict__ src,
                                                  const int* __restrict__ dst,
                                                  const int* __restrict__ hoff,
                                                  uint32_t* __restrict__ packed) {
    __shared__ int loff[NBUCKET];
    int blk = blockIdx.x, t = threadIdx.x;
    for (int i = t; i < NBUCKET; i += 256) loff[i] = hoff[i * NBE + blk];
    __syncthreads();
    int e0 = blk * ECHUNK;
    int e1 = e0 + ECHUNK; if (e1 > N_EDGES) e1 = N_EDGES;
    for (int e = e0 + t; e < e1; e += 256) {
        int d = dst[e];
        int pos = atomicAdd(&loff[d >> 8], 1);
        packed[pos] = ((uint32_t)src[e] << 8) | (uint32_t)(d & 255);
    }
}

// ---------------- fused finalize: hist + padded scan + sentinel CSR, fixed-cap buckets ---

__global__ __launch_bounds__(256) void finalize_k(const uint32_t* __restrict__ packed,
                                                  const int* __restrict__ hoff,
                                                  int* __restrict__ csr,
                                                  int* __restrict__ deg,
                                                  int* __restrict__ prowst) {
    __shared__ int lhist[256];
    __shared__ int ssc[256];
    __shared__ int lcur[256];
    __shared__ int s_pcnt;
    __shared__ uint32_t lpk[PCAP];
    __shared__ int lcsr[PCAP];
    int b = blockIdx.x, t = threadIdx.x;
    int base = hoff[b * NBE];
    int next = (b + 1 < NBUCKET) ? hoff[(b + 1) * NBE] : N_EDGES;
    int cnt = next - base;
    lhist[t] = 0;
    __syncthreads();
    bool fit = (cnt <= PCAP);
    if (fit) {
        for (int i = t; i < cnt; i += 256) {
            uint32_t pk = packed[base + i];
            lpk[i] = pk;
            atomicAdd(&lhist[pk & 255u], 1);
        }
    } else {
        for (int i = t; i < cnt; i += 256) atomicAdd(&lhist[packed[base + i] & 255u], 1);
    }
    __syncthreads();
    int d = lhist[t];
    int pd = (d + 7) & ~7;
    ssc[t] = pd;
    __syncthreads();
    int val = pd;
    for (int off = 1; off < 256; off <<= 1) {
        int x = (t >= off) ? ssc[t - off] : 0;
        __syncthreads();
        val += x;
        ssc[t] = val;
        __syncthreads();
    }
    int excl = val - pd;
    lcur[t] = excl;
    if (t == 255) s_pcnt = val;
    int node = (b << 8) + t;
    if (node < N_NODES) { deg[node] = d; prowst[node] = b * PCAP + excl; }
    __syncthreads();
    int pcnt = s_pcnt;
    int cbase = b * PCAP;
    if (fit && pcnt <= PCAP) {
        for (int i = t; i < pcnt; i += 256) lcsr[i] = SENTINEL;
        __syncthreads();
        for (int i = t; i < cnt; i += 256) {
            uint32_t pk = lpk[i];
            int pos = atomicAdd(&lcur[pk & 255u], 1);
            lcsr[pos] = (int)(pk >> 8);
        }
        __syncthreads();
        for (int i = t; i < pcnt; i += 256) csr[cbase + i] = lcsr[i];
    } else {  // statistically unreachable (+32 sigma); stays within slice
        int lim = pcnt < PCAP ? pcnt : PCAP;
        for (int i = t; i < lim; i += 256) csr[cbase + i] = SENTINEL;
        __syncthreads();
        for (int i = t; i < cnt; i += 256) {
            uint32_t pk = packed[base + i];
            int pos = atomicAdd(&lcur[pk & 255u], 1);
            if (pos < PCAP) csr[cbase + pos] = (int)(pk >> 8);
        }
    }
}

// ---------------- layer-1 mean aggregation: 2 nodes/wave, coalesced gather ----
// half-wave (32 lanes) owns one node; lane covers 4 B of the 128 B fp8 row.
// v3: software-pipelined — next iteration's csr indices prefetched while the current
// gathers are in flight (breaks the csr->gather serial chain). Sum order unchanged
// -> bit-identical output (absmax canary 0.0703125).

__global__ void aggregate_k(const int* __restrict__ csr, const int* __restrict__ prowst,
                            const int* __restrict__ deg,
                            const uint32_t* __restrict__ inf8, uint32_t* __restrict__ outf8) {
    int gw = (blockIdx.x * blockDim.x + threadIdx.x) >> 6;
    int lane = threadIdx.x & 63;
    int c = lane & 31, p = lane >> 5;
    int node = 2 * gw + p;                 // grid exact: 50000 waves x 2 = 100000
    int start = prowst[node];
    int d = deg[node];
    int pd = (d + 7) & ~7;
    f32x2 s01 = (f32x2){0.f, 0.f}, s23 = (f32x2){0.f, 0.f};
    int cur[8];
#pragma unroll
    for (int u = 0; u < 8; u++) cur[u] = (pd > 0) ? csr[start + u] : SENTINEL;
    for (int j = 0; j < pd; j += 8) {
        uint32_t q[8];
#pragma unroll
        for (int u = 0; u < 8; u++) q[u] = inf8[(cur[u] << 5) + c];   // issue gathers
        int nxt[8];
        if (j + 8 < pd) {
#pragma unroll
            for (int u = 0; u < 8; u++) nxt[u] = csr[start + j + 8 + u];  // prefetch
        } else {
#pragma unroll
            for (int u = 0; u < 8; u++) nxt[u] = cur[u];
        }
#pragma unroll
        for (int u = 0; u < 8; u++) {                                  // consume gathers
            s01 += __builtin_amdgcn_cvt_pk_f32_fp8((int)q[u], false);
            s23 += __builtin_amdgcn_cvt_pk_f32_fp8((int)q[u], true);
        }
#pragma unroll
        for (int u = 0; u < 8; u++) cur[u] = nxt[u];
    }
    float inv = 1.0f / (float)(d > 0 ? d : 1);
    int pk = __builtin_amdgcn_cvt_pk_fp8_f32(s01[0] * inv, s01[1] * inv, 0, false);
    pk = __builtin_amdgcn_cvt_pk_fp8_f32(s23[0] * inv, s23[1] * inv, pk, true);
    outf8[node * 32 + c] = (uint32_t)pk;   // 128 B/row contiguous per half-wave
}

// ---------------- fused GEMM1+GEMM2: per 128-row block, both layers, no hb round-trip ----
// A1 fragments read from fp8 aggregate (exact fp8->bf16 replay; e4m3 subset of bf16);
// A2 (root) stays fp32 — r14 proved fp8-x in the root term exceeds the error budget.
// A fragments hoisted out of the nh loop (r12). z bf16 (r11).

__global__ __launch_bounds__(256, 2) void gemm12_k(const uint32_t* __restrict__ abf8,
                                                   const float* __restrict__ x,
                                                   const uint16_t* __restrict__ wT1,
                                                   const float* __restrict__ b1,
                                                   const uint16_t* __restrict__ wT2,
                                                   const float* __restrict__ b2,
                                                   uint8_t* __restrict__ g,
                                                   uint16_t* __restrict__ zb) {
    __shared__ uint16_t lwA[64 * 256];   // 32 KB: wT1-half, then wT2, then fp8 epilogue
    __shared__ uint16_t lhb[128 * 128];  // 32 KB: h tile (XOR-chunk), then z bf16 epilogue
    int t = threadIdx.x;
    int rowblk = blockIdx.x;
    if (rowblk == 0 && t < 16)
        ((uint32_t*)(g + (size_t)N_NODES * 64))[t] = 0u;  // sentinel zero row

    int wave = t >> 6;
    int lane = t & 63;
    int m0 = rowblk * 128 + wave * 32;
    int mr = lane & 15, quad = lane >> 4;

    const uint32_t* A1[2];
    const float* A2[2];
#pragma unroll
    for (int s = 0; s < 2; s++) {
        int row = m0 + s * 16 + mr;
        if (row > N_NODES - 1) row = N_NODES - 1;   // clamp (stores still guarded)
        A1[s] = abf8 + (size_t)row * 32 + quad * 2;
        A2[s] = x + (size_t)row * 128 + quad * 8;
    }

    // ---------------- hoisted A-fragment loads (once per block; overlap wT1 stage) ----
    bf16x8 afr[8][2];
#pragma unroll
    for (int kt = 0; kt < 8; kt++) {
#pragma unroll
        for (int s = 0; s < 2; s++) {
            if (kt < 4) {
                uint2 w = *reinterpret_cast<const uint2*>(A1[s] + kt * 8);
                f32x2 a0 = __builtin_amdgcn_cvt_pk_f32_fp8((int)w.x, false);
                f32x2 a1 = __builtin_amdgcn_cvt_pk_f32_fp8((int)w.x, true);
                f32x2 a2 = __builtin_amdgcn_cvt_pk_f32_fp8((int)w.y, false);
                f32x2 a3 = __builtin_amdgcn_cvt_pk_f32_fp8((int)w.y, true);
                union { uint32_t w[4]; bf16x8 v; } cv;
                cv.w[0] = pack_bf16x2(a0[0], a0[1]);
                cv.w[1] = pack_bf16x2(a1[0], a1[1]);
                cv.w[2] = pack_bf16x2(a2[0], a2[1]);
                cv.w[3] = pack_bf16x2(a3[0], a3[1]);
                afr[kt][s] = cv.v;
            } else {
                const float* ap = A2[s] + (kt - 4) * 32;
                float4 f0 = *reinterpret_cast<const float4*>(ap);
                float4 f1 = *reinterpret_cast<const float4*>(ap + 4);
                union { uint16_t u[8]; bf16x8 v; } cv;
                cv.u[0] = f_to_bf16(f0.x); cv.u[1] = f_to_bf16(f0.y);
                cv.u[2] = f_to_bf16(f0.z); cv.u[3] = f_to_bf16(f0.w);
                cv.u[4] = f_to_bf16(f1.x); cv.u[5] = f_to_bf16(f1.y);
                cv.u[6] = f_to_bf16(f1.z); cv.u[7] = f_to_bf16(f1.w);
                afr[kt][s] = cv.v;
            }
        }
    }

    // ---------------- phase 1: two col-halves of h ----------------
    for (int nh = 0; nh < 2; nh++) {
        {   // stage wT1-half: global chunk (row nh*64+r, cc) -> lds r*32 + (cc^(r&31))
            const uint4* gsrc = (const uint4*)wT1;
            uint4* ldst = (uint4*)lwA;
            for (int i = t; i < 2048; i += 256) {
                int r = i >> 5, cc = i & 31;
                ldst[(r << 5) + (cc ^ (r & 31))] = gsrc[((nh * 64 + r) << 5) + cc];
            }
        }
        __syncthreads();

        f32x4 acc[4][2];
#pragma unroll
        for (int nt = 0; nt < 4; nt++)
#pragma unroll
            for (int s = 0; s < 2; s++) acc[nt][s] = (f32x4){0.f, 0.f, 0.f, 0.f};

#pragma unroll
        for (int kt = 0; kt < 8; kt++) {
#pragma unroll
            for (int nt = 0; nt < 4; nt++) {
                int brow = nt * 16 + mr;              // local 0..63
                int chunk = kt * 4 + quad;
                const uint16_t* bp = lwA + (brow << 8) + ((chunk ^ (brow & 31)) << 3);
                bf16x8 b = *reinterpret_cast<const bf16x8*>(bp);
#pragma unroll
                for (int s = 0; s < 2; s++)
                    acc[nt][s] = __builtin_amdgcn_mfma_f32_16x16x32_bf16(afr[kt][s], b, acc[nt][s], 0, 0, 0);
            }
        }
        __syncthreads();   // lwA reads done (safe to restage next iter / wT2)

        // bias+relu -> lhb (h cols nh*64 .. nh*64+63), XOR-chunk layout
#pragma unroll
        for (int nt = 0; nt < 4; nt++) {
            int col = nh * 64 + nt * 16 + mr;        // global h col 0..127
            float bias = b1[col];
            int c2 = col >> 3, clo = col & 7;
#pragma unroll
            for (int s = 0; s < 2; s++) {
#pragma unroll
                for (int r = 0; r < 4; r++) {
                    int lrow = wave * 32 + s * 16 + quad * 4 + r;   // 0..127
                    float v = acc[nt][s][r] + bias;
                    v = v > 0.f ? v : 0.f;
                    lhb[(lrow << 7) + ((c2 ^ (lrow & 15)) << 3) + clo] = f_to_bf16(v);
                }
            }
        }
        // no barrier needed here: lhb writes only conflict with phase-2 reads,
        // guarded by the barrier after wT2 staging
    }

    // ---------------- phase 2: [g|z] = h @ wT2 ----------------
    {   // stage full wT2: chunk i = (r = i>>4, cc = i&15) -> lds r*16 + (cc^(r&15))
        const uint4* gsrc = (const uint4*)wT2;
        uint4* ldst = (uint4*)lwA;
        for (int i = t; i < 2048; i += 256) {
            int r = i >> 4, cc = i & 15;
            ldst[(r << 4) + (cc ^ (r & 15))] = gsrc[(r << 4) + cc];
        }
    }
    __syncthreads();   // wT2 staged AND all lhb writes visible

    f32x4 acc2[8][2];
#pragma unroll
    for (int nt = 0; nt < 8; nt++)
#pragma unroll
        for (int s = 0; s < 2; s++) acc2[nt][s] = (f32x4){0.f, 0.f, 0.f, 0.f};

#pragma unroll
    for (int kt = 0; kt < 4; kt++) {
        bf16x8 av[2];
#pragma unroll
        for (int s = 0; s < 2; s++) {
            int row = wave * 32 + s * 16 + mr;       // local 0..127
            int chunk = kt * 4 + quad;
            const uint16_t* ap = lhb + (row << 7) + ((chunk ^ (row & 15)) << 3);
            av[s] = *reinterpret_cast<const bf16x8*>(ap);
        }
#pragma unroll
        for (int nt = 0; nt < 8; nt++) {
            int brow = nt * 16 + mr;                 // product col 0..127
            int chunk = kt * 4 + quad;
            const uint16_t* bp = lwA + (brow << 7) + ((chunk ^ (brow & 15)) << 3);
            bf16x8 b = *reinterpret_cast<const bf16x8*>(bp);
#pragma unroll
            for (int s = 0; s < 2; s++)
                acc2[nt][s] = __builtin_amdgcn_mfma_f32_16x16x32_bf16(av[s], b, acc2[nt][s], 0, 0, 0);
        }
    }

    // ---------------- epilogues: stage both outputs in LDS, store coalesced ----
    __syncthreads();   // all lhb + lwA reads done; both buffers reusable
    {
        // z (product cols 64..127) -> bf16 into lhb as [128][72] (stride 144B)
#pragma unroll
        for (int nt = 4; nt < 8; nt++) {
            int zcol = nt * 16 + mr - 64;            // 0..63
            float bias = b2[zcol];
#pragma unroll
            for (int s = 0; s < 2; s++) {
#pragma unroll
                for (int r = 0; r < 4; r++) {
                    int lrow = wave * 32 + s * 16 + quad * 4 + r;
                    lhb[lrow * 72 + zcol] = f_to_bf16(acc2[nt][s][r] + bias);
                }
            }
        }
        // g (product cols 0..63) -> fp8 into lwA as [128][80] bytes
        uint8_t* ep8 = (uint8_t*)lwA;
#pragma unroll
        for (int nt = 0; nt < 4; nt++) {
            int col = nt * 16 + mr;
#pragma unroll
            for (int s = 0; s < 2; s++) {
#pragma unroll
                for (int r = 0; r < 4; r++) {
                    int lrow = wave * 32 + s * 16 + quad * 4 + r;
                    float v = acc2[nt][s][r];
                    int pk = __builtin_amdgcn_cvt_pk_fp8_f32(v, v, 0, false);
                    ep8[lrow * 80 + col] = (uint8_t)(pk & 0xff);
                }
            }
        }
        __syncthreads();
        int rows0 = rowblk * 128;
        // g store: 128 rows x 64 B = 512 x 16B chunks
        for (int c2 = t; c2 < 512; c2 += 256) {
            int r = c2 >> 2, part = c2 & 3;
            int grow = rows0 + r;
            if (grow < N_NODES) {
                uint4 v = *reinterpret_cast<const uint4*>(ep8 + r * 80 + part * 16);
                *reinterpret_cast<uint4*>(g + (size_t)grow * 64 + part * 16) = v;
            }
        }
        // z store: 128 rows x 128 B (64 bf16) = 1024 x 16B chunks
        for (int c2 = t; c2 < 1024; c2 += 256) {
            int r = c2 >> 3, part = c2 & 7;
            int grow = rows0 + r;
            if (grow < N_NODES) {
                uint4 v = *reinterpret_cast<const uint4*>(lhb + r * 72 + part * 8);
                *reinterpret_cast<uint4*>(zb + (size_t)grow * 64 + part * 8) = v;
            }
        }
    }
}

// ---------------- layer-2 aggregation: 4 nodes/wave, coalesced gather ----
// quarter-wave (16 lanes) owns one node; lane covers 4 B of the 64 B fp8 row.
// v2: software-pipelined csr prefetch (same as aggregate_k). z bf16 read.

__global__ void agg2_k(const int* __restrict__ csr, const int* __restrict__ prowst,
                       const int* __restrict__ deg,
                       const uint32_t* __restrict__ g4, const uint16_t* __restrict__ zb,
                       float* __restrict__ out) {
    int gw = (blockIdx.x * blockDim.x + threadIdx.x) >> 6;
    int lane = threadIdx.x & 63;
    int c = lane & 15, q4 = lane >> 4;
    int node = 4 * gw + q4;                // grid exact: 25000 waves x 4 = 100000
    int start = prowst[node];
    int d = deg[node];
    int pd = (d + 7) & ~7;
    f32x2 s01 = (f32x2){0.f, 0.f}, s23 = (f32x2){0.f, 0.f};
    int cur[8];
#pragma unroll
    for (int u = 0; u < 8; u++) cur[u] = (pd > 0) ? csr[start + u] : SENTINEL;
    for (int j = 0; j < pd; j += 8) {
        uint32_t q[8];
#pragma unroll
        for (int u = 0; u < 8; u++) q[u] = g4[(cur[u] << 4) + c];   // issue gathers
        int nxt[8];
        if (j + 8 < pd) {
#pragma unroll
            for (int u = 0; u < 8; u++) nxt[u] = csr[start + j + 8 + u];  // prefetch
        } else {
#pragma unroll
            for (int u = 0; u < 8; u++) nxt[u] = cur[u];
        }
#pragma unroll
        for (int u = 0; u < 8; u++) {                                // consume gathers
            s01 += __builtin_amdgcn_cvt_pk_f32_fp8((int)q[u], false);
            s23 += __builtin_amdgcn_cvt_pk_f32_fp8((int)q[u], true);
        }
#pragma unroll
        for (int u = 0; u < 8; u++) cur[u] = nxt[u];
    }
    float inv = 1.0f / (float)(d > 0 ? d : 1);
    uint2 zw = ((const uint2*)zb)[node * 16 + c];   // 4 bf16 = cols 4c..4c+3
    float4 o;
    o.x = s01[0] * inv + __uint_as_float((zw.x & 0xffffu) << 16);
    o.y = s01[1] * inv + __uint_as_float(zw.x & 0xffff0000u);
    o.z = s23[0] * inv + __uint_as_float((zw.y & 0xffffu) << 16);
    o.w = s23[1] * inv + __uint_as_float(zw.y & 0xffff0000u);
    ((float4*)out)[node * 16 + c] = o;     // full-wave store, 4 rows / instr
}

// ---------------- launch ----------------

extern "C" void kernel_launch(void* const* d_in, const int* in_sizes, int n_in,
                              void* d_out, int out_size, void* d_ws, size_t ws_size,
                              hipStream_t stream) {
    const float* x   = (const float*)d_in[0];
    const int*  ei   = (const int*)d_in[1];
    const float* W1l = (const float*)d_in[2];
    const float* b1  = (const float*)d_in[3];
    const float* W1r = (const float*)d_in[4];
    const float* W2l = (const float*)d_in[5];
    const float* b2  = (const float*)d_in[6];
    const float* W2r = (const float*)d_in[7];
    float* out = (float*)d_out;

    const int* srcv = ei;            // edge_index[0]
    const int* dstv = ei + N_EDGES;  // edge_index[1]

    char* ws = (char*)d_ws;
    int*      deg      = (int*)(ws + 0);              // 100000 ints
    int*      prowst   = (int*)(ws + 401408);         // 100000 ints (padded row starts)
    int*      partials = (int*)(ws + 802816);         // 150 ints
    int*      csr      = (int*)(ws + 1209344);        // 391*PCAP ints = 9.6 MB -> 10818560
    uint16_t* wT1      = (uint16_t*)(ws + 13809664);  // 64 KB
    uint16_t* wT2      = (uint16_t*)(ws + 13875200);  // 32 KB
    uint8_t*  g        = (uint8_t*)(ws + 13907968);   // fp8 g (6.4 MB + 64B sentinel) -> 20308032
    uint16_t* zb       = (uint16_t*)(ws + 20308096);  // bf16 z (12.8 MB) -> 33108096
    uint32_t* abf8     = (uint32_t*)(ws + 39507968);  // fp8 aggregate (12.8 MB) -> 52307968
    // scratch region (former hb slot; consumed before gemm12 runs; stream-ordered):
    uint32_t* packed   = (uint32_t*)(ws + 65107968);          // 6.4 MB
    int*      hoff     = (int*)(ws + 65107968 + 6400000);     // 611 KB
    uint32_t* xf8      = (uint32_t*)(ws + 65107968 + 7013376);// 12.8 MB + 128

    // fused prep: hist + fp8 cast + weight transpose (independent block ranges)
    prep_k<<<NBE + 6250 + 192, 256, 0, stream>>>(dstv, x, W1l, W1r, W2l, W2r,
                                                 hoff, xf8, wT1, wT2);
    // scan hist matrix -> bucket-major global offsets
    scan1_k<<<NB_SCAN, 256, 0, stream>>>(hoff, partials, HM);
    scan3_k<<<(HM + 255) / 256, 256, 0, stream>>>(hoff, partials, HM);
    // partition edges into bucket-contiguous packed array
    scatter2_k<<<NBE, 256, 0, stream>>>(srcv, dstv, hoff, packed);
    // per-bucket padded CSR + deg + prowst (fixed-cap slices)
    finalize_k<<<NBUCKET, 256, 0, stream>>>(packed, hoff, csr, deg, prowst);

    // layer 1 aggregation: aggr(x_fp8) -> abf8 (fp8)
    aggregate_k<<<12500, 256, 0, stream>>>(csr, prowst, deg, xf8, abf8);
    // fused both GEMMs: h = relu([aggr|x]@wT1^T + b1) in LDS; [g|zb] = h@wT2 (+b2 on z)
    gemm12_k<<<GEMM_ROWBLKS, 256, 0, stream>>>(abf8, x, wT1, b1, wT2, b2, g, zb);
    // layer 2 aggregation: out = mean-aggr(g) + z
    agg2_k<<<6250, 256, 0, stream>>>(csr, prowst, deg, (const uint32_t*)g, zb, out);
}